// Round 5
// baseline (195.889 us; speedup 1.0000x reference)
//
#include <hip/hip_runtime.h>

#define DDIM 256
#define HDIM 128
#define KLEN 1024
// 2*log2(e): exp2(SCL*x) == e^{2x}
#define SCL 2.8853900817779268f

// ============ Projection -> Eq/Ek = exp2(SCL * in@W) ============
// v2 (proven 33us): wave-uniform W (scalar s_load path) x per-lane rows.
// Block = 64 rows x 32 h = 4 waves; each wave owns 8 h, each lane owns 1 row.
// A-tile (64 rows x 64 d) in LDS, XOR-swizzled on 16B granules so each
// lane's ds_read_b128 of its own row is <=2-way (free). W operands are
// wave-uniform -> scalar loads, costing no VALU/VMEM/LDS bandwidth.
// Grid 1088 (4.25 blocks/CU): 1024 key blocks (XCD-swizzled) + 64 query.
// Output layouts: Eq row-major [row][128], Ek [b][h][k], exp2 applied.
__global__ __launch_bounds__(256) void proj_kernel(
    const float* __restrict__ queries, const float* __restrict__ keys,
    const float* __restrict__ W_q, const float* __restrict__ W_k,
    float* __restrict__ Eq, float* __restrict__ Ek)
{
    __shared__ union {
        float a[64 * 64];    // 16 KB A-tile (swizzled)
        float t[32][68];     // epilogue transpose staging (keys), pad 64->68
    } sm;

    const int tid  = threadIdx.x;
    const int lane = tid & 63;
    const int wav  = tid >> 6;

    int blk = blockIdx.x;
    bool iskey; int b = 0, kc0 = 0, hb, row0;
    const float* in; const float* W;
    if (blk < 1024) {
        iskey = true;
        int xcd = blk & 7, s = blk >> 3;
        b = ((s >> 6) << 3) | xcd;
        int r6 = s & 63;
        kc0 = (r6 >> 2) << 6;     // 16 k-chunks of 64
        hb  = (r6 & 3) << 5;      // 4 h-chunks of 32
        row0 = b * KLEN + kc0;
        in = keys; W = W_k;
    } else {
        iskey = false;
        int qrb = blk - 1024;     // 0..63
        row0 = (qrb >> 2) << 6;
        hb   = (qrb & 3) << 5;
        in = queries; W = W_q;
    }

    // wave-uniform h-base -> W accesses become scalar loads
    const int hg8 = __builtin_amdgcn_readfirstlane(wav << 3);
    const float* Wu = W + hb + hg8;

    // staging: 4 x 16B granules per thread per 64-d step, coalesced reads
    const int srow = tid >> 4;        // 0..15 (+16*i covers 64 rows)
    const int sgd  = tid & 15;        // 16B granule within 64-d row slice
    const float* gsrc = in + (size_t)(row0 + srow) * DDIM + (sgd << 2);

    float4 pf0 = *(const float4*)(gsrc);
    float4 pf1 = *(const float4*)(gsrc + 16 * DDIM);
    float4 pf2 = *(const float4*)(gsrc + 32 * DDIM);
    float4 pf3 = *(const float4*)(gsrc + 48 * DDIM);

    float acc[8];
    #pragma unroll
    for (int c = 0; c < 8; c++) acc[c] = 0.f;

    // XOR-swizzled LDS write offsets (float index): granule ^= (row & 7)
    const int w0 = (srow)      * 64 + ((sgd ^ ((srow)      & 7)) << 2);
    const int w1 = (srow + 16) * 64 + ((sgd ^ ((srow + 16) & 7)) << 2);
    const int w2 = (srow + 32) * 64 + ((sgd ^ ((srow + 32) & 7)) << 2);
    const int w3 = (srow + 48) * 64 + ((sgd ^ ((srow + 48) & 7)) << 2);

    for (int dt0 = 0; dt0 < DDIM; dt0 += 64) {
        *(float4*)(sm.a + w0) = pf0;
        *(float4*)(sm.a + w1) = pf1;
        *(float4*)(sm.a + w2) = pf2;
        *(float4*)(sm.a + w3) = pf3;
        __syncthreads();
        if (dt0 < DDIM - 64) {        // prefetch next d-tile under compute
            const float* g2 = gsrc + dt0 + 64;
            pf0 = *(const float4*)(g2);
            pf1 = *(const float4*)(g2 + 16 * DDIM);
            pf2 = *(const float4*)(g2 + 32 * DDIM);
            pf3 = *(const float4*)(g2 + 48 * DDIM);
        }
        const float* arow = sm.a + lane * 64;
        const int lx = lane & 7;
        #pragma unroll
        for (int d4 = 0; d4 < 64; d4 += 4) {
            float4 a = *(const float4*)(arow + ((((d4 >> 2)) ^ lx) << 2));
            const float* wr = Wu + (size_t)(dt0 + d4) * HDIM;
            #pragma unroll
            for (int c = 0; c < 8; c++) acc[c] = fmaf(a.x, wr[c],            acc[c]);
            #pragma unroll
            for (int c = 0; c < 8; c++) acc[c] = fmaf(a.y, wr[HDIM + c],     acc[c]);
            #pragma unroll
            for (int c = 0; c < 8; c++) acc[c] = fmaf(a.z, wr[2 * HDIM + c], acc[c]);
            #pragma unroll
            for (int c = 0; c < 8; c++) acc[c] = fmaf(a.w, wr[3 * HDIM + c], acc[c]);
        }
        __syncthreads();   // compute done before next tile overwrites LDS
    }

    float e[8];
    #pragma unroll
    for (int c = 0; c < 8; c++) e[c] = __builtin_amdgcn_exp2f(SCL * acc[c]);

    if (!iskey) {
        float* dst = Eq + (size_t)(row0 + lane) * HDIM + hb + hg8;
        *(float4*)(dst)     = make_float4(e[0], e[1], e[2], e[3]);
        *(float4*)(dst + 4) = make_float4(e[4], e[5], e[6], e[7]);
    } else {
        // transpose 64k x 32h -> t[h][k], then coalesced 256B-row stores
        #pragma unroll
        for (int c = 0; c < 8; c++) sm.t[(wav << 3) + c][lane] = e[c];
        __syncthreads();
        float* dstb = Ek + (size_t)b * HDIM * KLEN + (size_t)hb * KLEN + kc0;
        #pragma unroll
        for (int i = 0; i < 2; i++) {
            int g = tid + (i << 8);
            int h = g >> 4, k4 = (g & 15) << 2;
            float4 o = *(const float4*)(&sm.t[h][k4]);
            *(float4*)(dstb + (size_t)h * KLEN + k4) = o;
        }
    }
}

// ============ Unnormalized scores E = exp(s), masked-zero; row totals T ============
// v2: normalization-free streaming (softmax shift-invariance: the global
// Sum(w) constant and the max-subtract both cancel in E/T; s in +-18 so
// exp is fp32-safe). Grid 256 = (16 qg) x (2 bh) x (8 xcd), XCD-matched to
// where proj wrote Ek[b]. Block = (b, 4 q), 256 thr, thread = 4q x 4k.
// Ek streamed through LDS in 8h x 1024k = 32KB chunks (coalesced b128
// stage, conflict-free b128 reads, reg-prefetch under compute); eq/w2 in
// regs per chunk. Per-CU/chunk: trans 1024cy > VALU 512 > LDS 432 ->
// trans-bound by construction. One block owns the full k-row -> T final.
__global__ __launch_bounds__(256) void score_kernel(
    const float* __restrict__ Eq, const float* __restrict__ Ek,
    const float* __restrict__ w_v, const int* __restrict__ valid_lens,
    float* __restrict__ E, float* __restrict__ T)
{
    __shared__ float ekt[8][KLEN];   // 32 KB h-chunk of Ek
    __shared__ float eqs[4][HDIM];   // 2 KB Eq rows
    __shared__ float w2s[HDIM];      // -2*w_v
    __shared__ float tred[4][4];     // [wave][q] partial T

    const int tid = threadIdx.x;
    const int lane = tid & 63, wav = tid >> 6;
    int m = blockIdx.x;
    int xcd = m & 7, bh = (m >> 3) & 1, qg = m >> 4;
    int b = (bh << 3) | xcd;
    int bq0 = b * 64 + qg * 4;

    // stage Eq rows + w2 once
    if (tid < HDIM) w2s[tid] = -2.0f * w_v[tid];
    #pragma unroll
    for (int i = 0; i < 2; i++) {
        int idx = tid + (i << 8);            // 512 slots
        int q = idx >> 7, h = idx & 127;
        eqs[q][h] = Eq[(size_t)(bq0 + q) * HDIM + h];
    }

    const float* ekb = Ek + (size_t)b * HDIM * KLEN;
    const int k0 = tid << 2;

    // prefetch chunk 0: 8 rows x 16B per thread
    float4 pf[8];
    #pragma unroll
    for (int i = 0; i < 8; i++)
        pf[i] = *(const float4*)(ekb + (size_t)i * KLEN + k0);

    float4 acc4[4];
    #pragma unroll
    for (int j = 0; j < 4; j++) acc4[j] = make_float4(0.f, 0.f, 0.f, 0.f);

    for (int c = 0; c < 16; c++) {
        __syncthreads();                     // prior chunk reads done
        #pragma unroll
        for (int i = 0; i < 8; i++)
            *(float4*)(&ekt[i][k0]) = pf[i];
        __syncthreads();
        if (c < 15) {                        // prefetch next chunk
            const float* nx = ekb + (size_t)(c + 1) * 8 * KLEN + k0;
            #pragma unroll
            for (int i = 0; i < 8; i++)
                pf[i] = *(const float4*)(nx + (size_t)i * KLEN);
        }
        // eq/w2 registers for this h-chunk
        const int c8 = c << 3;
        float eqr[4][8], w2r[8];
        #pragma unroll
        for (int j = 0; j < 4; j++) {
            *(float4*)(&eqr[j][0]) = *(const float4*)(&eqs[j][c8]);
            *(float4*)(&eqr[j][4]) = *(const float4*)(&eqs[j][c8 + 4]);
        }
        *(float4*)(&w2r[0]) = *(const float4*)(&w2s[c8]);
        *(float4*)(&w2r[4]) = *(const float4*)(&w2s[c8 + 4]);

        #pragma unroll
        for (int hh = 0; hh < 8; hh++) {
            float4 ek = *(const float4*)(&ekt[hh][k0]);
            float w2v = w2r[hh];
            #pragma unroll
            for (int j = 0; j < 4; j++) {
                float eqv = eqr[j][hh];
                acc4[j].x = fmaf(w2v, __builtin_amdgcn_rcpf(fmaf(eqv, ek.x, 1.f)), acc4[j].x);
                acc4[j].y = fmaf(w2v, __builtin_amdgcn_rcpf(fmaf(eqv, ek.y, 1.f)), acc4[j].y);
                acc4[j].z = fmaf(w2v, __builtin_amdgcn_rcpf(fmaf(eqv, ek.z, 1.f)), acc4[j].z);
                acc4[j].w = fmaf(w2v, __builtin_amdgcn_rcpf(fmaf(eqv, ek.w, 1.f)), acc4[j].w);
            }
        }
    }

    // epilogue: E = exp(acc) masked to 0 beyond vlen; per-row totals
    int vlen = valid_lens[b];
    float ts[4];
    #pragma unroll
    for (int j = 0; j < 4; j++) {
        float4 ev;
        ev.x = (k0 + 0 < vlen) ? __expf(acc4[j].x) : 0.f;
        ev.y = (k0 + 1 < vlen) ? __expf(acc4[j].y) : 0.f;
        ev.z = (k0 + 2 < vlen) ? __expf(acc4[j].z) : 0.f;
        ev.w = (k0 + 3 < vlen) ? __expf(acc4[j].w) : 0.f;
        *(float4*)(E + (size_t)(bq0 + j) * KLEN + k0) = ev;
        ts[j] = (ev.x + ev.y) + (ev.z + ev.w);
    }
    #pragma unroll
    for (int j = 0; j < 4; j++) {
        float t = ts[j];
        #pragma unroll
        for (int off = 32; off > 0; off >>= 1) t += __shfl_xor(t, off, 64);
        if (lane == 0) tred[wav][j] = t;
    }
    __syncthreads();
    if (tid < 4) {
        float t = tred[0][tid] + tred[1][tid] + tred[2][tid] + tred[3][tid];
        T[bq0 + tid] = t;
    }
}

// ============ E @ V (k-half partials, unnormalized) ============
// Grid EXACTLY 256 = (16 b x 8 qt x 2 k-half), XCD-swizzled -> 1 block/CU.
// 4 waves; wave w owns exclusive k-slice of 128. Per k: one fully-coalesced
// global f4 (wave = entire 1KB V row), two broadcast ds_read_b128 for E[8q],
// 32 fma. vlen-clamped (E==0 beyond -> round-to-4 safe). LDS slab reduce;
// unconditional stores -> poison-safe.
__global__ __launch_bounds__(256) void av_kernel(
    const float* __restrict__ E, const float* __restrict__ values,
    const int* __restrict__ valid_lens, float* __restrict__ part)
{
    __shared__ union {
        float  pt[512][8];          // 16 KB [k-local][q]
        float4 slab[4][8][64];      // 32 KB [wave][q][d4]
    } sm;

    int blk = blockIdx.x;
    int xcd = blk & 7, s = blk >> 3;      // s: 0..31
    int b = ((s >> 4) << 3) | xcd;
    int r = s & 15, qt = r >> 1, kh = r & 1;
    int tid = threadIdx.x, lane = tid & 63, w = tid >> 6;
    int vlen = valid_lens[b];
    int bq0 = b * 64 + qt * 8;
    int kbase = kh << 9;                  // 0 or 512

    // stage E[8q][512k] -> pt[k][q]
    #pragma unroll
    for (int i = 0; i < 4; i++) {
        int slot = tid + (i << 8);        // 1024 float4 slots
        int q = slot >> 7, k4 = (slot & 127) << 2;
        float4 pv = *(const float4*)(E + (size_t)(bq0 + q) * KLEN + kbase + k4);
        sm.pt[k4 + 0][q] = pv.x;
        sm.pt[k4 + 1][q] = pv.y;
        sm.pt[k4 + 2][q] = pv.z;
        sm.pt[k4 + 3][q] = pv.w;
    }
    __syncthreads();

    int kw = w << 7;                      // wave's k-local base
    int cnt = vlen - (kbase + kw); cnt = cnt < 0 ? 0 : (cnt > 128 ? 128 : cnt);
    int cnt4 = (cnt + 3) & ~3;
    const float* vb = values + ((size_t)b * KLEN + kbase + kw) * DDIM + (lane << 2);

    float4 acc[8];
    #pragma unroll
    for (int q = 0; q < 8; q++) acc[q] = make_float4(0.f, 0.f, 0.f, 0.f);

    for (int k = 0; k < cnt4; k += 4) {
        #pragma unroll
        for (int j = 0; j < 4; j++) {
            float4 v  = *(const float4*)(vb + (size_t)(k + j) * DDIM);
            float4 p0 = *(const float4*)(&sm.pt[kw + k + j][0]);
            float4 p1 = *(const float4*)(&sm.pt[kw + k + j][4]);
            float pq[8] = {p0.x, p0.y, p0.z, p0.w, p1.x, p1.y, p1.z, p1.w};
            #pragma unroll
            for (int q = 0; q < 8; q++) {
                acc[q].x = fmaf(pq[q], v.x, acc[q].x);
                acc[q].y = fmaf(pq[q], v.y, acc[q].y);
                acc[q].z = fmaf(pq[q], v.z, acc[q].z);
                acc[q].w = fmaf(pq[q], v.w, acc[q].w);
            }
        }
    }

    __syncthreads();               // pt reads done; overwrite with slab
    #pragma unroll
    for (int q = 0; q < 8; q++) sm.slab[w][q][lane] = acc[q];
    __syncthreads();
    #pragma unroll
    for (int e = 0; e < 2; e++) {
        int slot = (tid << 1) | e;         // 512 output f4 slots
        int q = slot >> 6, d4 = slot & 63;
        float4 a = sm.slab[0][q][d4];
        #pragma unroll
        for (int g = 1; g < 4; g++) {
            float4 t = sm.slab[g][q][d4];
            a.x += t.x; a.y += t.y; a.z += t.z; a.w += t.w;
        }
        *(float4*)(part + ((size_t)kh * 1024 + bq0 + q) * DDIM + (d4 << 2)) = a;
    }
}

// ============ sum 2 k-half partials, normalize by T ============
__global__ __launch_bounds__(256) void combine_kernel(
    const float* __restrict__ part, const float* __restrict__ T,
    float* __restrict__ out)
{
    int i = blockIdx.x * 256 + threadIdx.x;        // 65536 float4 slots
    const float4* p4 = (const float4*)part;
    float4 a = p4[i];
    float4 v = p4[65536 + i];
    float inv = 1.0f / T[i >> 6];
    a.x = (a.x + v.x) * inv; a.y = (a.y + v.y) * inv;
    a.z = (a.z + v.z) * inv; a.w = (a.w + v.w) * inv;
    ((float4*)out)[i] = a;
}

extern "C" void kernel_launch(void* const* d_in, const int* in_sizes, int n_in,
                              void* d_out, int out_size, void* d_ws, size_t ws_size,
                              hipStream_t stream) {
    const float* queries    = (const float*)d_in[0]; // [16,64,256]
    const float* keys       = (const float*)d_in[1]; // [16,1024,256]
    const float* values     = (const float*)d_in[2]; // [16,1024,256]
    const int*   valid_lens = (const int*)d_in[3];   // [16]
    const float* W_q        = (const float*)d_in[4]; // [256,128]
    const float* W_k        = (const float*)d_in[5]; // [256,128]
    const float* w_v        = (const float*)d_in[6]; // [128]

    float* Eq   = (float*)d_ws;            // 1024*128     = 512 KB
    float* Ek   = Eq + 131072;             // 16*128*1024  = 8 MB
    float* E    = Ek + 2097152;            // 1024*1024    = 4 MB (unnormalized)
    float* T    = E + 1048576;             // 1024 floats
    float* part = Ek;                      // alias: Ek dead after score; 2 MB

    proj_kernel<<<1088, 256, 0, stream>>>(queries, keys, W_q, W_k, Eq, Ek);
    score_kernel<<<256, 256, 0, stream>>>(Eq, Ek, w_v, valid_lens, E, T);
    av_kernel<<<256, 256, 0, stream>>>(E, values, valid_lens, part);
    combine_kernel<<<256, 256, 0, stream>>>(part, T, (float*)d_out);
}

// Round 6
// 154.651 us; speedup vs baseline: 1.2667x; 1.2667x over previous
//
#include <hip/hip_runtime.h>

#define DDIM 256
#define HDIM 128
#define KLEN 1024
// 2*log2(e): exp2(SCL*x) == e^{2x}
#define SCL 2.8853900817779268f

// ============ Projection -> Eq/Ek = exp2(SCL * in@W) ============
// v2 (proven 33us): wave-uniform W (scalar s_load path) x per-lane rows.
// Block = 64 rows x 32 h = 4 waves; each wave owns 8 h, each lane owns 1 row.
// A-tile (64 rows x 64 d) in LDS, XOR-swizzled on 16B granules so each
// lane's ds_read_b128 of its own row is <=2-way (free). W operands are
// wave-uniform -> scalar loads, costing no VALU/VMEM/LDS bandwidth.
// Grid 1088 (4.25 blocks/CU): 1024 key blocks (XCD-swizzled) + 64 query.
// Output layouts: Eq row-major [row][128], Ek [b][h][k], exp2 applied.
__global__ __launch_bounds__(256) void proj_kernel(
    const float* __restrict__ queries, const float* __restrict__ keys,
    const float* __restrict__ W_q, const float* __restrict__ W_k,
    float* __restrict__ Eq, float* __restrict__ Ek)
{
    __shared__ union {
        float a[64 * 64];    // 16 KB A-tile (swizzled)
        float t[32][68];     // epilogue transpose staging (keys), pad 64->68
    } sm;

    const int tid  = threadIdx.x;
    const int lane = tid & 63;
    const int wav  = tid >> 6;

    int blk = blockIdx.x;
    bool iskey; int b = 0, kc0 = 0, hb, row0;
    const float* in; const float* W;
    if (blk < 1024) {
        iskey = true;
        int xcd = blk & 7, s = blk >> 3;
        b = ((s >> 6) << 3) | xcd;
        int r6 = s & 63;
        kc0 = (r6 >> 2) << 6;     // 16 k-chunks of 64
        hb  = (r6 & 3) << 5;      // 4 h-chunks of 32
        row0 = b * KLEN + kc0;
        in = keys; W = W_k;
    } else {
        iskey = false;
        int qrb = blk - 1024;     // 0..63
        row0 = (qrb >> 2) << 6;
        hb   = (qrb & 3) << 5;
        in = queries; W = W_q;
    }

    // wave-uniform h-base -> W accesses become scalar loads
    const int hg8 = __builtin_amdgcn_readfirstlane(wav << 3);
    const float* Wu = W + hb + hg8;

    // staging: 4 x 16B granules per thread per 64-d step, coalesced reads
    const int srow = tid >> 4;        // 0..15 (+16*i covers 64 rows)
    const int sgd  = tid & 15;        // 16B granule within 64-d row slice
    const float* gsrc = in + (size_t)(row0 + srow) * DDIM + (sgd << 2);

    float4 pf0 = *(const float4*)(gsrc);
    float4 pf1 = *(const float4*)(gsrc + 16 * DDIM);
    float4 pf2 = *(const float4*)(gsrc + 32 * DDIM);
    float4 pf3 = *(const float4*)(gsrc + 48 * DDIM);

    float acc[8];
    #pragma unroll
    for (int c = 0; c < 8; c++) acc[c] = 0.f;

    // XOR-swizzled LDS write offsets (float index): granule ^= (row & 7)
    const int w0 = (srow)      * 64 + ((sgd ^ ((srow)      & 7)) << 2);
    const int w1 = (srow + 16) * 64 + ((sgd ^ ((srow + 16) & 7)) << 2);
    const int w2 = (srow + 32) * 64 + ((sgd ^ ((srow + 32) & 7)) << 2);
    const int w3 = (srow + 48) * 64 + ((sgd ^ ((srow + 48) & 7)) << 2);

    for (int dt0 = 0; dt0 < DDIM; dt0 += 64) {
        *(float4*)(sm.a + w0) = pf0;
        *(float4*)(sm.a + w1) = pf1;
        *(float4*)(sm.a + w2) = pf2;
        *(float4*)(sm.a + w3) = pf3;
        __syncthreads();
        if (dt0 < DDIM - 64) {        // prefetch next d-tile under compute
            const float* g2 = gsrc + dt0 + 64;
            pf0 = *(const float4*)(g2);
            pf1 = *(const float4*)(g2 + 16 * DDIM);
            pf2 = *(const float4*)(g2 + 32 * DDIM);
            pf3 = *(const float4*)(g2 + 48 * DDIM);
        }
        const float* arow = sm.a + lane * 64;
        const int lx = lane & 7;
        #pragma unroll
        for (int d4 = 0; d4 < 64; d4 += 4) {
            float4 a = *(const float4*)(arow + ((((d4 >> 2)) ^ lx) << 2));
            const float* wr = Wu + (size_t)(dt0 + d4) * HDIM;
            #pragma unroll
            for (int c = 0; c < 8; c++) acc[c] = fmaf(a.x, wr[c],            acc[c]);
            #pragma unroll
            for (int c = 0; c < 8; c++) acc[c] = fmaf(a.y, wr[HDIM + c],     acc[c]);
            #pragma unroll
            for (int c = 0; c < 8; c++) acc[c] = fmaf(a.z, wr[2 * HDIM + c], acc[c]);
            #pragma unroll
            for (int c = 0; c < 8; c++) acc[c] = fmaf(a.w, wr[3 * HDIM + c], acc[c]);
        }
        __syncthreads();   // compute done before next tile overwrites LDS
    }

    float e[8];
    #pragma unroll
    for (int c = 0; c < 8; c++) e[c] = __builtin_amdgcn_exp2f(SCL * acc[c]);

    if (!iskey) {
        float* dst = Eq + (size_t)(row0 + lane) * HDIM + hb + hg8;
        *(float4*)(dst)     = make_float4(e[0], e[1], e[2], e[3]);
        *(float4*)(dst + 4) = make_float4(e[4], e[5], e[6], e[7]);
    } else {
        // transpose 64k x 32h -> t[h][k], then coalesced 256B-row stores
        #pragma unroll
        for (int c = 0; c < 8; c++) sm.t[(wav << 3) + c][lane] = e[c];
        __syncthreads();
        float* dstb = Ek + (size_t)b * HDIM * KLEN + (size_t)hb * KLEN + kc0;
        #pragma unroll
        for (int i = 0; i < 2; i++) {
            int g = tid + (i << 8);
            int h = g >> 4, k4 = (g & 15) << 2;
            float4 o = *(const float4*)(&sm.t[h][k4]);
            *(float4*)(dstb + (size_t)h * KLEN + k4) = o;
        }
    }
}

// ============ Unnormalized scores E = exp(s), masked-zero ============
// v3: normalization-free (Sum(w) constant and max-shift cancel in E/T;
// s in +-18 -> fp32-safe). Row totals moved to av (byproduct there).
// Grid 1024 = (16 b x 8 qt x 8 kq), XCD-matched to proj's Ek[b] placement;
// 256 thr (4 waves) -> 4 blocks/CU, 16 waves/CU (12.5 KB LDS). Thread =
// 2q x 2k. Ek streamed in 16h x 128k = 8 KB chunks, reg-prefetched one
// chunk ahead; all LDS accesses conflict-free by construction. Per-wave
// per-chunk: trans 512cy > LDS ~130cy -> trans-bound with 4 waves/SIMD.
__global__ __launch_bounds__(256) void score_kernel(
    const float* __restrict__ Eq, const float* __restrict__ Ek,
    const float* __restrict__ w_v, const int* __restrict__ valid_lens,
    float* __restrict__ E)
{
    __shared__ float ekt[16][128];   // 8 KB h-chunk x k-slice
    __shared__ float eqs[8][HDIM];   // 4 KB Eq rows
    __shared__ float w2s[HDIM];      // -2*w_v

    const int tid = threadIdx.x;
    const int lane = tid & 63, wav = tid >> 6;
    int blk = blockIdx.x;
    int xcd = blk & 7, s = blk >> 3;          // 0..127
    int b = ((s >> 6) << 3) | xcd;
    int r = s & 63;
    int qt = r >> 3, kq = r & 7;
    int bq0 = b * 64 + qt * 8;
    int k0g = kq << 7;                        // global k base of 128-slice

    if (tid < HDIM) w2s[tid] = -2.0f * w_v[tid];
    #pragma unroll
    for (int i = 0; i < 4; i++) {
        int slot = tid + (i << 8);            // 1024 slots
        int q = slot >> 7, h = slot & 127;
        eqs[q][h] = Eq[(size_t)(bq0 + q) * HDIM + h];
    }

    const float* ekb = Ek + (size_t)b * HDIM * KLEN + k0g;
    // prefetch chunk 0: 16 rows x 32 granules(16B) = 512 slots, 2/thread
    float4 pf[2];
    #pragma unroll
    for (int i = 0; i < 2; i++) {
        int slot = tid + (i << 8);
        int row = slot >> 5, g = slot & 31;
        pf[i] = *(const float4*)(ekb + (size_t)row * KLEN + (g << 2));
    }

    const int q0 = wav << 1;                  // wave's q-pair
    const int kl = lane << 1;                 // lane's 2 k within slice
    float2 acc[2] = {make_float2(0.f, 0.f), make_float2(0.f, 0.f)};

    for (int c = 0; c < 8; c++) {
        __syncthreads();                      // prior chunk reads done
        #pragma unroll
        for (int i = 0; i < 2; i++) {
            int slot = tid + (i << 8);
            int row = slot >> 5, g = slot & 31;
            *(float4*)(&ekt[row][g << 2]) = pf[i];
        }
        __syncthreads();
        if (c < 7) {                          // prefetch next chunk
            const float* nx = ekb + (size_t)((c + 1) << 4) * KLEN;
            #pragma unroll
            for (int i = 0; i < 2; i++) {
                int slot = tid + (i << 8);
                int row = slot >> 5, g = slot & 31;
                pf[i] = *(const float4*)(nx + (size_t)row * KLEN + (g << 2));
            }
        }
        const int c16 = c << 4;
        #pragma unroll
        for (int h4 = 0; h4 < 16; h4 += 4) {
            float4 eqa = *(const float4*)(&eqs[q0][c16 + h4]);
            float4 eqb = *(const float4*)(&eqs[q0 + 1][c16 + h4]);
            float4 w2v = *(const float4*)(&w2s[c16 + h4]);
            float ea[4] = {eqa.x, eqa.y, eqa.z, eqa.w};
            float eb[4] = {eqb.x, eqb.y, eqb.z, eqb.w};
            float wv[4] = {w2v.x, w2v.y, w2v.z, w2v.w};
            #pragma unroll
            for (int hh = 0; hh < 4; hh++) {
                float2 ek = *(const float2*)(&ekt[h4 + hh][kl]);
                float w2 = wv[hh];
                acc[0].x = fmaf(w2, __builtin_amdgcn_rcpf(fmaf(ea[hh], ek.x, 1.f)), acc[0].x);
                acc[0].y = fmaf(w2, __builtin_amdgcn_rcpf(fmaf(ea[hh], ek.y, 1.f)), acc[0].y);
                acc[1].x = fmaf(w2, __builtin_amdgcn_rcpf(fmaf(eb[hh], ek.x, 1.f)), acc[1].x);
                acc[1].y = fmaf(w2, __builtin_amdgcn_rcpf(fmaf(eb[hh], ek.y, 1.f)), acc[1].y);
            }
        }
    }

    int vlen = valid_lens[b];
    int kg = k0g + kl;
    #pragma unroll
    for (int j = 0; j < 2; j++) {
        float2 ev;
        ev.x = (kg     < vlen) ? __expf(acc[j].x) : 0.f;
        ev.y = (kg + 1 < vlen) ? __expf(acc[j].y) : 0.f;
        *(float2*)(E + (size_t)(bq0 + q0 + j) * KLEN + kg) = ev;
    }
}

// ============ E @ V (k-half partials) + T partials ============
// Grid EXACTLY 256 = (16 b x 8 qt x 2 k-half), XCD-swizzled -> 1 block/CU.
// 4 waves; wave w owns exclusive k-slice of 128. Per k: one fully-coalesced
// global f4 (wave = entire 1KB V row), two broadcast ds_read_b128 for E[8q],
// 32 fma + 8 adds (T byproduct; pq wave-uniform so acct is wave-uniform).
// vlen-clamped (E==0 beyond -> round-to-4 safe). LDS slab reduce;
// unconditional stores -> poison-safe.
__global__ __launch_bounds__(256) void av_kernel(
    const float* __restrict__ E, const float* __restrict__ values,
    const int* __restrict__ valid_lens, float* __restrict__ part,
    float* __restrict__ Tp)
{
    __shared__ union {
        float  pt[512][8];          // 16 KB [k-local][q]
        float4 slab[4][8][64];      // 32 KB [wave][q][d4]
    } sm;
    __shared__ float tslab[4][8];

    int blk = blockIdx.x;
    int xcd = blk & 7, s = blk >> 3;      // s: 0..31
    int b = ((s >> 4) << 3) | xcd;
    int r = s & 15, qt = r >> 1, kh = r & 1;
    int tid = threadIdx.x, lane = tid & 63, w = tid >> 6;
    int vlen = valid_lens[b];
    int bq0 = b * 64 + qt * 8;
    int kbase = kh << 9;                  // 0 or 512

    // stage E[8q][512k] -> pt[k][q]
    #pragma unroll
    for (int i = 0; i < 4; i++) {
        int slot = tid + (i << 8);        // 1024 float4 slots
        int q = slot >> 7, k4 = (slot & 127) << 2;
        float4 pv = *(const float4*)(E + (size_t)(bq0 + q) * KLEN + kbase + k4);
        sm.pt[k4 + 0][q] = pv.x;
        sm.pt[k4 + 1][q] = pv.y;
        sm.pt[k4 + 2][q] = pv.z;
        sm.pt[k4 + 3][q] = pv.w;
    }
    __syncthreads();

    int kw = w << 7;                      // wave's k-local base
    int cnt = vlen - (kbase + kw); cnt = cnt < 0 ? 0 : (cnt > 128 ? 128 : cnt);
    int cnt4 = (cnt + 3) & ~3;
    const float* vb = values + ((size_t)b * KLEN + kbase + kw) * DDIM + (lane << 2);

    float4 acc[8];
    float acct[8];
    #pragma unroll
    for (int q = 0; q < 8; q++) { acc[q] = make_float4(0.f, 0.f, 0.f, 0.f); acct[q] = 0.f; }

    for (int k = 0; k < cnt4; k += 4) {
        #pragma unroll
        for (int j = 0; j < 4; j++) {
            float4 v  = *(const float4*)(vb + (size_t)(k + j) * DDIM);
            float4 p0 = *(const float4*)(&sm.pt[kw + k + j][0]);
            float4 p1 = *(const float4*)(&sm.pt[kw + k + j][4]);
            float pq[8] = {p0.x, p0.y, p0.z, p0.w, p1.x, p1.y, p1.z, p1.w};
            #pragma unroll
            for (int q = 0; q < 8; q++) {
                acc[q].x = fmaf(pq[q], v.x, acc[q].x);
                acc[q].y = fmaf(pq[q], v.y, acc[q].y);
                acc[q].z = fmaf(pq[q], v.z, acc[q].z);
                acc[q].w = fmaf(pq[q], v.w, acc[q].w);
                acct[q] += pq[q];
            }
        }
    }

    __syncthreads();               // pt reads done; overwrite with slab
    #pragma unroll
    for (int q = 0; q < 8; q++) sm.slab[w][q][lane] = acc[q];
    if (lane == 0) {
        #pragma unroll
        for (int q = 0; q < 8; q++) tslab[w][q] = acct[q];
    }
    __syncthreads();
    #pragma unroll
    for (int e = 0; e < 2; e++) {
        int slot = (tid << 1) | e;         // 512 output f4 slots
        int q = slot >> 6, d4 = slot & 63;
        float4 a = sm.slab[0][q][d4];
        #pragma unroll
        for (int g = 1; g < 4; g++) {
            float4 t = sm.slab[g][q][d4];
            a.x += t.x; a.y += t.y; a.z += t.z; a.w += t.w;
        }
        *(float4*)(part + ((size_t)kh * 1024 + bq0 + q) * DDIM + (d4 << 2)) = a;
    }
    if (tid < 8) {
        float t = tslab[0][tid] + tslab[1][tid] + tslab[2][tid] + tslab[3][tid];
        Tp[(size_t)kh * 1024 + bq0 + tid] = t;
    }
}

// ============ sum 2 k-half partials, normalize by T ============
__global__ __launch_bounds__(256) void combine_kernel(
    const float* __restrict__ part, const float* __restrict__ Tp,
    float* __restrict__ out)
{
    int i = blockIdx.x * 256 + threadIdx.x;        // 65536 float4 slots
    int row = i >> 6;                              // 0..1023 (b*64+q)
    const float4* p4 = (const float4*)part;
    float4 a = p4[i];
    float4 v = p4[65536 + i];
    float inv = 1.0f / (Tp[row] + Tp[1024 + row]);
    a.x = (a.x + v.x) * inv; a.y = (a.y + v.y) * inv;
    a.z = (a.z + v.z) * inv; a.w = (a.w + v.w) * inv;
    ((float4*)out)[i] = a;
}

extern "C" void kernel_launch(void* const* d_in, const int* in_sizes, int n_in,
                              void* d_out, int out_size, void* d_ws, size_t ws_size,
                              hipStream_t stream) {
    const float* queries    = (const float*)d_in[0]; // [16,64,256]
    const float* keys       = (const float*)d_in[1]; // [16,1024,256]
    const float* values     = (const float*)d_in[2]; // [16,1024,256]
    const int*   valid_lens = (const int*)d_in[3];   // [16]
    const float* W_q        = (const float*)d_in[4]; // [256,128]
    const float* W_k        = (const float*)d_in[5]; // [256,128]
    const float* w_v        = (const float*)d_in[6]; // [128]

    float* Eq   = (float*)d_ws;            // 1024*128     = 512 KB
    float* Ek   = Eq + 131072;             // 16*128*1024  = 8 MB
    float* E    = Ek + 2097152;            // 1024*1024    = 4 MB (unnormalized)
    float* Tp   = E + 1048576;             // 2048 floats (k-half T partials)
    float* part = Ek;                      // alias: Ek dead after score; 2 MB

    proj_kernel<<<1088, 256, 0, stream>>>(queries, keys, W_q, W_k, Eq, Ek);
    score_kernel<<<1024, 256, 0, stream>>>(Eq, Ek, w_v, valid_lens, E);
    av_kernel<<<256, 256, 0, stream>>>(E, values, valid_lens, part, Tp);
    combine_kernel<<<256, 256, 0, stream>>>(part, Tp, (float*)d_out);
}

// Round 7
// 136.304 us; speedup vs baseline: 1.4371x; 1.1346x over previous
//
#include <hip/hip_runtime.h>

#define DDIM 256
#define HDIM 128
#define KLEN 1024
// 2*log2(e): exp2(SCL*x) == e^{2x}
#define SCL 2.8853900817779268f

// ============ Projection -> Eq/Ek = exp2(SCL * in@W) ============
// v2 (proven 33us): wave-uniform W (scalar s_load path) x per-lane rows.
// Block = 64 rows x 32 h = 4 waves; each wave owns 8 h, each lane owns 1 row.
// A-tile (64 rows x 64 d) in LDS, XOR-swizzled on 16B granules so each
// lane's ds_read_b128 of its own row is <=2-way (free). W operands are
// wave-uniform -> scalar loads, costing no VALU/VMEM/LDS bandwidth.
// Grid 1088 (4.25 blocks/CU): 1024 key blocks (XCD-swizzled) + 64 query.
// Output layouts: Eq row-major [row][128], Ek [b][h][k], exp2 applied.
__global__ __launch_bounds__(256) void proj_kernel(
    const float* __restrict__ queries, const float* __restrict__ keys,
    const float* __restrict__ W_q, const float* __restrict__ W_k,
    float* __restrict__ Eq, float* __restrict__ Ek)
{
    __shared__ union {
        float a[64 * 64];    // 16 KB A-tile (swizzled)
        float t[32][68];     // epilogue transpose staging (keys), pad 64->68
    } sm;

    const int tid  = threadIdx.x;
    const int lane = tid & 63;
    const int wav  = tid >> 6;

    int blk = blockIdx.x;
    bool iskey; int b = 0, kc0 = 0, hb, row0;
    const float* in; const float* W;
    if (blk < 1024) {
        iskey = true;
        int xcd = blk & 7, s = blk >> 3;
        b = ((s >> 6) << 3) | xcd;
        int r6 = s & 63;
        kc0 = (r6 >> 2) << 6;     // 16 k-chunks of 64
        hb  = (r6 & 3) << 5;      // 4 h-chunks of 32
        row0 = b * KLEN + kc0;
        in = keys; W = W_k;
    } else {
        iskey = false;
        int qrb = blk - 1024;     // 0..63
        row0 = (qrb >> 2) << 6;
        hb   = (qrb & 3) << 5;
        in = queries; W = W_q;
    }

    // wave-uniform h-base -> W accesses become scalar loads
    const int hg8 = __builtin_amdgcn_readfirstlane(wav << 3);
    const float* Wu = W + hb + hg8;

    // staging: 4 x 16B granules per thread per 64-d step, coalesced reads
    const int srow = tid >> 4;        // 0..15 (+16*i covers 64 rows)
    const int sgd  = tid & 15;        // 16B granule within 64-d row slice
    const float* gsrc = in + (size_t)(row0 + srow) * DDIM + (sgd << 2);

    float4 pf0 = *(const float4*)(gsrc);
    float4 pf1 = *(const float4*)(gsrc + 16 * DDIM);
    float4 pf2 = *(const float4*)(gsrc + 32 * DDIM);
    float4 pf3 = *(const float4*)(gsrc + 48 * DDIM);

    float acc[8];
    #pragma unroll
    for (int c = 0; c < 8; c++) acc[c] = 0.f;

    // XOR-swizzled LDS write offsets (float index): granule ^= (row & 7)
    const int w0 = (srow)      * 64 + ((sgd ^ ((srow)      & 7)) << 2);
    const int w1 = (srow + 16) * 64 + ((sgd ^ ((srow + 16) & 7)) << 2);
    const int w2 = (srow + 32) * 64 + ((sgd ^ ((srow + 32) & 7)) << 2);
    const int w3 = (srow + 48) * 64 + ((sgd ^ ((srow + 48) & 7)) << 2);

    for (int dt0 = 0; dt0 < DDIM; dt0 += 64) {
        *(float4*)(sm.a + w0) = pf0;
        *(float4*)(sm.a + w1) = pf1;
        *(float4*)(sm.a + w2) = pf2;
        *(float4*)(sm.a + w3) = pf3;
        __syncthreads();
        if (dt0 < DDIM - 64) {        // prefetch next d-tile under compute
            const float* g2 = gsrc + dt0 + 64;
            pf0 = *(const float4*)(g2);
            pf1 = *(const float4*)(g2 + 16 * DDIM);
            pf2 = *(const float4*)(g2 + 32 * DDIM);
            pf3 = *(const float4*)(g2 + 48 * DDIM);
        }
        const float* arow = sm.a + lane * 64;
        const int lx = lane & 7;
        #pragma unroll
        for (int d4 = 0; d4 < 64; d4 += 4) {
            float4 a = *(const float4*)(arow + ((((d4 >> 2)) ^ lx) << 2));
            const float* wr = Wu + (size_t)(dt0 + d4) * HDIM;
            #pragma unroll
            for (int c = 0; c < 8; c++) acc[c] = fmaf(a.x, wr[c],            acc[c]);
            #pragma unroll
            for (int c = 0; c < 8; c++) acc[c] = fmaf(a.y, wr[HDIM + c],     acc[c]);
            #pragma unroll
            for (int c = 0; c < 8; c++) acc[c] = fmaf(a.z, wr[2 * HDIM + c], acc[c]);
            #pragma unroll
            for (int c = 0; c < 8; c++) acc[c] = fmaf(a.w, wr[3 * HDIM + c], acc[c]);
        }
        __syncthreads();   // compute done before next tile overwrites LDS
    }

    float e[8];
    #pragma unroll
    for (int c = 0; c < 8; c++) e[c] = __builtin_amdgcn_exp2f(SCL * acc[c]);

    if (!iskey) {
        float* dst = Eq + (size_t)(row0 + lane) * HDIM + hb + hg8;
        *(float4*)(dst)     = make_float4(e[0], e[1], e[2], e[3]);
        *(float4*)(dst + 4) = make_float4(e[4], e[5], e[6], e[7]);
    } else {
        // transpose 64k x 32h -> t[h][k], then coalesced 256B-row stores
        #pragma unroll
        for (int c = 0; c < 8; c++) sm.t[(wav << 3) + c][lane] = e[c];
        __syncthreads();
        float* dstb = Ek + (size_t)b * HDIM * KLEN + (size_t)hb * KLEN + kc0;
        #pragma unroll
        for (int i = 0; i < 2; i++) {
            int g = tid + (i << 8);
            int h = g >> 4, k4 = (g & 15) << 2;
            float4 o = *(const float4*)(&sm.t[h][k4]);
            *(float4*)(dstb + (size_t)h * KLEN + k4) = o;
        }
    }
}

// ============ FUSED scores + E@V (normalization-free) ============
// Grid 1024 = (16 b x 8 qt x 8 kq), XCD-matched to proj's Ek[b] placement;
// 256 thr (4 waves) -> 4 blocks/CU, 16 waves/CU.
// Phase 1 (score, v1's proven direct-L2 regime): thread = 2q x 2k over all
// 128 h; Ek streamed from global (coalesced 512B/wave float2 loads, 8-deep
// reg dual-buffer); (eq0,eq1,w2) as ONE broadcast float4/h from LDS. E tile
// (8q x 128k, masked-zero exp) -> 4 KB LDS. One barrier.
// Phase 2 (av v4's proven loop): wave owns exclusive 32 k; per k one
// fully-coalesced 1KB/wave V float4 row + 2 broadcast b128 E reads ->
// 32 fma + 8 T-adds (wave-uniform). Slab reduce -> part[kq] + Tp[kq].
// Softmax algebra: Sum(w) constant and max-shift cancel in (E@V)/T;
// |s|<~25 -> exp fp32-safe. Unconditional stores -> poison-safe.
__global__ __launch_bounds__(256) void score_av_kernel(
    const float* __restrict__ Eq, const float* __restrict__ Ek,
    const float* __restrict__ w_v, const int* __restrict__ valid_lens,
    const float* __restrict__ values,
    float* __restrict__ part, float* __restrict__ Tp)
{
    __shared__ union {
        struct {
            float4 eqw[4][HDIM];   // (eq_q0, eq_q1, -2w, 0) per wave  8 KB
            float  el[128][8];     // E tile [k][q]                    4 KB
        } p;
        float4 slab[4][8][64];     // 32 KB cross-wave reduce
    } sm;
    __shared__ float tslab[4][8];

    const int tid = threadIdx.x;
    const int lane = tid & 63, wav = tid >> 6;
    int blk = blockIdx.x;
    int xcd = blk & 7, s = blk >> 3;          // 0..127
    int b = ((s >> 6) << 3) | xcd;
    int r = s & 63;
    int qt = r >> 3, kq = r & 7;
    int bq0 = b * 64 + qt * 8;
    int k0g = kq << 7;                        // global k base of 128-slice
    int vlen = valid_lens[b];

    // ---- prologue: pack eqw (coalesced one-time global reads) ----
    #pragma unroll
    for (int i = 0; i < 2; i++) {
        int slot = tid + (i << 8);            // 512 slots = 4 waves x 128 h
        int w = slot >> 7, h = slot & 127;
        sm.p.eqw[w][h] = make_float4(
            Eq[(size_t)(bq0 + 2 * w) * HDIM + h],
            Eq[(size_t)(bq0 + 2 * w + 1) * HDIM + h],
            -2.0f * w_v[h], 0.f);
    }
    __syncthreads();

    // ---- phase 1: scores for (2q x 2k), h-streamed, 8-deep reg dbuf ----
    const int kl = lane << 1;                 // lane's 2 k within slice
    const float* ekp = Ek + (size_t)b * HDIM * KLEN + k0g + kl;
    float2 buf[8];
    #pragma unroll
    for (int j = 0; j < 8; j++)
        buf[j] = *(const float2*)(ekp + (size_t)j * KLEN);

    float2 acc0 = make_float2(0.f, 0.f), acc1 = make_float2(0.f, 0.f);
    for (int h0 = 0; h0 < HDIM; h0 += 8) {
        float2 nxt[8];
        if (h0 < HDIM - 8) {
            #pragma unroll
            for (int j = 0; j < 8; j++)
                nxt[j] = *(const float2*)(ekp + (size_t)(h0 + 8 + j) * KLEN);
        }
        #pragma unroll
        for (int j = 0; j < 8; j++) {
            float4 e = sm.p.eqw[wav][h0 + j];
            float2 ek = buf[j];
            acc0.x = fmaf(e.z, __builtin_amdgcn_rcpf(fmaf(e.x, ek.x, 1.f)), acc0.x);
            acc0.y = fmaf(e.z, __builtin_amdgcn_rcpf(fmaf(e.x, ek.y, 1.f)), acc0.y);
            acc1.x = fmaf(e.z, __builtin_amdgcn_rcpf(fmaf(e.y, ek.x, 1.f)), acc1.x);
            acc1.y = fmaf(e.z, __builtin_amdgcn_rcpf(fmaf(e.y, ek.y, 1.f)), acc1.y);
        }
        #pragma unroll
        for (int j = 0; j < 8; j++) buf[j] = nxt[j];
    }

    {   // masked exp -> E tile in LDS (el[k][q]); one-time write
        int kg = k0g + kl;
        float e00 = (kg     < vlen) ? __expf(acc0.x) : 0.f;   // q0, k
        float e01 = (kg + 1 < vlen) ? __expf(acc0.y) : 0.f;   // q0, k+1
        float e10 = (kg     < vlen) ? __expf(acc1.x) : 0.f;   // q1, k
        float e11 = (kg + 1 < vlen) ? __expf(acc1.y) : 0.f;   // q1, k+1
        *(float2*)(&sm.p.el[kl][2 * wav])     = make_float2(e00, e10);
        *(float2*)(&sm.p.el[kl + 1][2 * wav]) = make_float2(e01, e11);
    }
    __syncthreads();

    // ---- phase 2: E @ V, wave-exclusive 32-k slice ----
    int kw = wav << 5;                        // wave's k-local base
    int kg0 = k0g + kw;
    int cnt = vlen - kg0; cnt = cnt < 0 ? 0 : (cnt > 32 ? 32 : cnt);
    int cnt4 = (cnt + 3) & ~3;                // el == 0 beyond vlen -> safe
    const float* vb = values + ((size_t)b * KLEN + kg0) * DDIM + (lane << 2);

    float4 acc[8];
    float acct[8];
    #pragma unroll
    for (int q = 0; q < 8; q++) { acc[q] = make_float4(0.f, 0.f, 0.f, 0.f); acct[q] = 0.f; }

    for (int k = 0; k < cnt4; k += 4) {
        #pragma unroll
        for (int j = 0; j < 4; j++) {
            float4 v  = *(const float4*)(vb + (size_t)(k + j) * DDIM);
            float4 p0 = *(const float4*)(&sm.p.el[kw + k + j][0]);
            float4 p1 = *(const float4*)(&sm.p.el[kw + k + j][4]);
            float pq[8] = {p0.x, p0.y, p0.z, p0.w, p1.x, p1.y, p1.z, p1.w};
            #pragma unroll
            for (int q = 0; q < 8; q++) {
                acc[q].x = fmaf(pq[q], v.x, acc[q].x);
                acc[q].y = fmaf(pq[q], v.y, acc[q].y);
                acc[q].z = fmaf(pq[q], v.z, acc[q].z);
                acc[q].w = fmaf(pq[q], v.w, acc[q].w);
                acct[q] += pq[q];
            }
        }
    }

    __syncthreads();               // el reads done; overwrite with slab
    #pragma unroll
    for (int q = 0; q < 8; q++) sm.slab[wav][q][lane] = acc[q];
    if (lane == 0) {
        #pragma unroll
        for (int q = 0; q < 8; q++) tslab[wav][q] = acct[q];
    }
    __syncthreads();
    #pragma unroll
    for (int e = 0; e < 2; e++) {
        int slot = (tid << 1) | e;         // 512 output f4 slots
        int q = slot >> 6, d4 = slot & 63;
        float4 a = sm.slab[0][q][d4];
        #pragma unroll
        for (int g = 1; g < 4; g++) {
            float4 t = sm.slab[g][q][d4];
            a.x += t.x; a.y += t.y; a.z += t.z; a.w += t.w;
        }
        *(float4*)(part + ((size_t)kq * 1024 + bq0 + q) * DDIM + (d4 << 2)) = a;
    }
    if (tid < 8) {
        float t = tslab[0][tid] + tslab[1][tid] + tslab[2][tid] + tslab[3][tid];
        Tp[(size_t)kq * 1024 + bq0 + tid] = t;
    }
}

// ============ sum 8 kq-partials, normalize by T ============
__global__ __launch_bounds__(256) void combine_kernel(
    const float* __restrict__ part, const float* __restrict__ Tp,
    float* __restrict__ out)
{
    int i = blockIdx.x * 256 + threadIdx.x;        // 65536 float4 slots
    int row = i >> 6;                              // 0..1023 (b*64+q)
    const float4* p4 = (const float4*)part;
    float t = 0.f;
    #pragma unroll
    for (int j = 0; j < 8; j++) t += Tp[(size_t)j * 1024 + row];
    float inv = 1.0f / t;
    float4 a = p4[i];
    #pragma unroll
    for (int j = 1; j < 8; j++) {
        float4 v = p4[(size_t)j * 65536 + i];
        a.x += v.x; a.y += v.y; a.z += v.z; a.w += v.w;
    }
    a.x *= inv; a.y *= inv; a.z *= inv; a.w *= inv;
    ((float4*)out)[i] = a;
}

extern "C" void kernel_launch(void* const* d_in, const int* in_sizes, int n_in,
                              void* d_out, int out_size, void* d_ws, size_t ws_size,
                              hipStream_t stream) {
    const float* queries    = (const float*)d_in[0]; // [16,64,256]
    const float* keys       = (const float*)d_in[1]; // [16,1024,256]
    const float* values     = (const float*)d_in[2]; // [16,1024,256]
    const int*   valid_lens = (const int*)d_in[3];   // [16]
    const float* W_q        = (const float*)d_in[4]; // [256,128]
    const float* W_k        = (const float*)d_in[5]; // [256,128]
    const float* w_v        = (const float*)d_in[6]; // [128]

    float* Eq   = (float*)d_ws;            // 1024*128      = 512 KB
    float* Ek   = Eq + 131072;             // 16*128*1024   = 8 MB
    float* part = Ek + 2097152;            // 8*1024*256    = 8 MB (no alias: Ek live)
    float* Tp   = part + 2097152;          // 8*1024 floats = 32 KB

    proj_kernel<<<1088, 256, 0, stream>>>(queries, keys, W_q, W_k, Eq, Ek);
    score_av_kernel<<<1024, 256, 0, stream>>>(Eq, Ek, w_v, valid_lens, values, part, Tp);
    combine_kernel<<<256, 256, 0, stream>>>(part, Tp, (float*)d_out);
}